// Round 1
// baseline (270.045 us; speedup 1.0000x reference)
//
#include <hip/hip_runtime.h>

#define CDIM 512
#define NH 8
#define HWDIM 4096
#define TILE 256   // spatial positions per block

// Fold weights: wvT[c*8+n] = sum_j wqkv[(1024+64n+j)*512 + c]
//               wp [o*8+n] = sum_j wproj[o*512 + 64n + j]
__global__ __launch_bounds__(256) void prep_kernel(
    const float* __restrict__ wqkv, const float* __restrict__ wproj,
    float* __restrict__ wvT, float* __restrict__ wp) {
  int idx = blockIdx.x * 256 + threadIdx.x;
  if (idx < 4096) {
    int c = idx >> 3, n = idx & 7;
    const float* p = wqkv + (size_t)(1024 + n * 64) * CDIM + c;
    float s = 0.f;
#pragma unroll 8
    for (int j = 0; j < 64; ++j) s += p[(size_t)j * CDIM];
    wvT[idx] = s;
  } else if (idx < 8192) {
    int i2 = idx - 4096;
    int o = i2 >> 3, n = i2 & 7;
    const float* p = wproj + (size_t)o * CDIM + n * 64;
    float s = 0.f;
#pragma unroll 8
    for (int j = 0; j < 64; ++j) s += p[j];
    wp[i2] = s;
  }
}

// y[b,o,s] = bias[o] + sum_n wp[o,n] * (sum_c wvT[c,n] * x[b,c,s])
__global__ __launch_bounds__(256) void fused_kernel(
    const float* __restrict__ x, const float* __restrict__ bias,
    const float* __restrict__ wvT, const float* __restrict__ wp,
    float* __restrict__ y) {
  __shared__ __align__(16) float sWv[4096];            // [c][n]
  __shared__ __align__(16) float sWp[4096];            // [o][n]
  __shared__ __align__(16) float sB[512];
  __shared__ __align__(16) float sS[4][NH][TILE];      // per-wave partial S

  const int t = threadIdx.x;
  for (int i = t; i < 4096; i += 256) { sWv[i] = wvT[i]; sWp[i] = wp[i]; }
  for (int i = t; i < 512; i += 256) sB[i] = bias[i];
  __syncthreads();

  const int wave = t >> 6;
  const int lane = t & 63;
  const int pos0 = blockIdx.x * TILE;        // 256 | 4096 so blocks never straddle b
  const int b = pos0 >> 12;
  const int hw0 = pos0 & (HWDIM - 1);
  const float* xb = x + ((size_t)b * CDIM) * HWDIM + hw0 + lane * 4;

  // ---- phase 1: S[n, pos] partials; wave handles 128 channels ----
  float acc[NH][4];
#pragma unroll
  for (int n = 0; n < NH; ++n) {
    acc[n][0] = 0.f; acc[n][1] = 0.f; acc[n][2] = 0.f; acc[n][3] = 0.f;
  }

  const int c0 = wave * 128;
#pragma unroll 8
  for (int cc = 0; cc < 128; ++cc) {
    const int c = c0 + cc;
    const float4 xv = *(const float4*)(xb + (size_t)c * HWDIM);
    const float4 w0 = *(const float4*)&sWv[c * 8];
    const float4 w1 = *(const float4*)&sWv[c * 8 + 4];
    const float wn[8] = {w0.x, w0.y, w0.z, w0.w, w1.x, w1.y, w1.z, w1.w};
    const float xv4[4] = {xv.x, xv.y, xv.z, xv.w};
#pragma unroll
    for (int n = 0; n < NH; ++n) {
#pragma unroll
      for (int p = 0; p < 4; ++p) acc[n][p] = fmaf(wn[n], xv4[p], acc[n][p]);
    }
  }

#pragma unroll
  for (int n = 0; n < NH; ++n) {
    *(float4*)&sS[wave][n][lane * 4] =
        make_float4(acc[n][0], acc[n][1], acc[n][2], acc[n][3]);
  }
  __syncthreads();

  // ---- phase 2: reduce S across waves, expand to 512 outputs ----
  float S4[NH][4];
#pragma unroll
  for (int n = 0; n < NH; ++n) {
    const float4 a0 = *(const float4*)&sS[0][n][lane * 4];
    const float4 a1 = *(const float4*)&sS[1][n][lane * 4];
    const float4 a2 = *(const float4*)&sS[2][n][lane * 4];
    const float4 a3 = *(const float4*)&sS[3][n][lane * 4];
    S4[n][0] = a0.x + a1.x + a2.x + a3.x;
    S4[n][1] = a0.y + a1.y + a2.y + a3.y;
    S4[n][2] = a0.z + a1.z + a2.z + a3.z;
    S4[n][3] = a0.w + a1.w + a2.w + a3.w;
  }

  float* yb = y + ((size_t)b * CDIM) * HWDIM + hw0 + lane * 4;
  const int o0 = wave * 128;
#pragma unroll 4
  for (int oo = 0; oo < 128; ++oo) {
    const int o = o0 + oo;
    const float4 w0 = *(const float4*)&sWp[o * 8];
    const float4 w1 = *(const float4*)&sWp[o * 8 + 4];
    const float wn[8] = {w0.x, w0.y, w0.z, w0.w, w1.x, w1.y, w1.z, w1.w};
    const float bb = sB[o];
    float r[4] = {bb, bb, bb, bb};
#pragma unroll
    for (int n = 0; n < NH; ++n) {
#pragma unroll
      for (int p = 0; p < 4; ++p) r[p] = fmaf(wn[n], S4[n][p], r[p]);
    }
    *(float4*)(yb + (size_t)o * HWDIM) = make_float4(r[0], r[1], r[2], r[3]);
  }
}

extern "C" void kernel_launch(void* const* d_in, const int* in_sizes, int n_in,
                              void* d_out, int out_size, void* d_ws, size_t ws_size,
                              hipStream_t stream) {
  const float* x     = (const float*)d_in[0];
  const float* wqkv  = (const float*)d_in[1];
  const float* wproj = (const float*)d_in[2];
  const float* bproj = (const float*)d_in[3];
  float* y = (float*)d_out;

  float* wvT = (float*)d_ws;        // 4096 floats
  float* wp  = wvT + 4096;          // 4096 floats (32 KB total scratch)

  prep_kernel<<<32, 256, 0, stream>>>(wqkv, wproj, wvT, wp);
  fused_kernel<<<256, 256, 0, stream>>>(x, bproj, wvT, wp, y);
}